// Round 14
// baseline (56.254 us; speedup 1.0000x reference)
//
#include <hip/hip_runtime.h>
#include <stdint.h>

#define NFEAT 16
#define NCOLS 969            // 1 bias + 16 deg1 + 136 deg2 + 816 deg3
#define NROWS 65536
#define PASS_ROWS 32
#define TILE_ROWS 64
#define TILES_PER_BLOCK 4    // 256 blocks * 4 tiles * 64 rows = 65536
#define PASS_ELEMS (PASS_ROWS * NCOLS)   // 31008 dwords, flat-contiguous in out
#define NTHREADS 512

typedef float floatx4 __attribute__((ext_vector_type(4)));

// ---------------------------------------------------------------------------
// Static compute of cols [CBASE, CEND) of one row into packed LDS row.
// All 969 columns emitted in sklearn/jax reference order (verified absmax 0.0
// R1/R3-R13); out-of-range emits are compile-time dead. Scalar ds_write_b32:
// packed stride 969 -> banks (9*row + col) % 32; stride 9 coprime with 32 ->
// conflict-free. 60-col bodies fit the 256-VGPR cap of (512,2) without
// spilling (R13 verified: 47.0us ~= R11, no spill regression).
// ---------------------------------------------------------------------------
template<int CBASE, int CEND>
__device__ __forceinline__ void compute_range(const float* xr, float* ldsrow) {
    int col = 0;
#define EMIT(P) do { if (col >= CBASE && col < CEND) ldsrow[col] = (P); ++col; } while (0)
    EMIT(1.0f);                                   // bias
    #pragma unroll
    for (int i = 0; i < NFEAT; ++i) EMIT(xr[i]);  // degree 1
    #pragma unroll
    for (int i = 0; i < NFEAT; ++i)               // degree 2
        #pragma unroll
        for (int j = i; j < NFEAT; ++j) EMIT(xr[i] * xr[j]);
    #pragma unroll
    for (int i = 0; i < NFEAT; ++i)               // degree 3 (reuses x_i*x_j via CSE)
        #pragma unroll
        for (int j = i; j < NFEAT; ++j)
            #pragma unroll
            for (int k = j; k < NFEAT; ++k) EMIT((xr[i] * xr[j]) * xr[k]);
#undef EMIT
}

__device__ __forceinline__ void compute_dispatch(int range, const float* xr, float* ldsrow) {
    switch (range) {   // uniform per 32-lane half-wave -> 2 serial 32-lane bodies/wave
        case  0: compute_range<  0,  60>(xr, ldsrow); break;
        case  1: compute_range< 60, 120>(xr, ldsrow); break;
        case  2: compute_range<120, 180>(xr, ldsrow); break;
        case  3: compute_range<180, 240>(xr, ldsrow); break;
        case  4: compute_range<240, 300>(xr, ldsrow); break;
        case  5: compute_range<300, 360>(xr, ldsrow); break;
        case  6: compute_range<360, 420>(xr, ldsrow); break;
        case  7: compute_range<420, 480>(xr, ldsrow); break;
        case  8: compute_range<480, 540>(xr, ldsrow); break;
        case  9: compute_range<540, 600>(xr, ldsrow); break;
        case 10: compute_range<600, 660>(xr, ldsrow); break;
        case 11: compute_range<660, 720>(xr, ldsrow); break;
        case 12: compute_range<720, 780>(xr, ldsrow); break;
        case 13: compute_range<780, 840>(xr, ldsrow); break;
        case 14: compute_range<840, 900>(xr, ldsrow); break;
        case 15: compute_range<900, 969>(xr, ldsrow); break;
    }
}

// Store phase = flat copy of the packed LDS image: ds_read_b128 +
// global_store_dwordx4 nt (streaming: don't cycle the XCD L2 with 4MB of
// dirty lines per pass; protect x residency). 16B-aligned both sides.
__device__ __forceinline__ void store_pass(float* __restrict__ out, int rowbase,
                                           int tid, const float* lds) {
    floatx4* dst4 = (floatx4*)(out + (size_t)rowbase * NCOLS);
    const floatx4* lds4 = (const floatx4*)lds;
    #pragma unroll 4
    for (int g4 = tid; g4 < PASS_ELEMS / 4; g4 += NTHREADS)   // 7752 groups
        __builtin_nontemporal_store(lds4[g4], &dst4[g4]);
}

// Raw barrier WITHOUT vmcnt(0) drain: LDS visibility needs only lgkmcnt(0);
// in-flight global stores drain across the barrier while next pass computes.
__device__ __forceinline__ void lds_barrier() {
    asm volatile("s_waitcnt lgkmcnt(0)" ::: "memory");
    __builtin_amdgcn_s_barrier();
}

__global__ void __launch_bounds__(NTHREADS, 2)
poly_rows(const float* __restrict__ x, float* __restrict__ out) {
    __shared__ __align__(16) float lds[PASS_ROWS * NCOLS];   // 124,032 B -> 1 block/CU

    const int tid   = threadIdx.x;
    const int lrow  = tid & 31;                  // row within pass
    const int range = tid >> 5;                  // 0..15, uniform per 32-lane group
    float* ldsrow = &lds[lrow * NCOLS];

    const int tile0_row = blockIdx.x * TILES_PER_BLOCK * TILE_ROWS;

    // Preload tile 0's two x-rows per lane.
    const floatx4* xa = (const floatx4*)(x + (size_t)(tile0_row + lrow) * NFEAT);
    const floatx4* xb = (const floatx4*)(x + (size_t)(tile0_row + 32 + lrow) * NFEAT);
    floatx4 a0 = xa[0], a1 = xa[1], a2 = xa[2], a3 = xa[3];
    floatx4 b0 = xb[0], b1 = xb[1], b2 = xb[2], b3 = xb[3];

    for (int it = 0; it < TILES_PER_BLOCK; ++it) {
        const int row0 = tile0_row + it * TILE_ROWS;

        // Extract both passes' operands into SSA values now, freeing a*/b*
        // registers for the next-tile prefetch below.
        float xrA[NFEAT] = {a0[0],a0[1],a0[2],a0[3], a1[0],a1[1],a1[2],a1[3],
                            a2[0],a2[1],a2[2],a2[3], a3[0],a3[1],a3[2],a3[3]};
        float xrB[NFEAT] = {b0[0],b0[1],b0[2],b0[3], b1[0],b1[1],b1[2],b1[3],
                            b2[0],b2[1],b2[2],b2[3], b3[0],b3[1],b3[2],b3[3]};

        // ---- pass A: rows row0..row0+31 ----
        compute_dispatch(range, xrA, ldsrow);
        lds_barrier();
        store_pass(out, row0, tid, lds);
        lds_barrier();

        // Prefetch next tile's x-rows BEFORE store B issues its stores:
        // loads precede the ~15/wave stores in vmcnt order, so the wait for
        // x at the next tile's extract is vmcnt<=15 (no store drain), and the
        // loads get the whole store-B drain (~10.9k cyc) to complete.
        if (it + 1 < TILES_PER_BLOCK) {
            const int nrow = tile0_row + (it + 1) * TILE_ROWS;
            const floatx4* na = (const floatx4*)(x + (size_t)(nrow + lrow) * NFEAT);
            const floatx4* nb = (const floatx4*)(x + (size_t)(nrow + 32 + lrow) * NFEAT);
            a0 = na[0]; a1 = na[1]; a2 = na[2]; a3 = na[3];
            b0 = nb[0]; b1 = nb[1]; b2 = nb[2]; b3 = nb[3];
        }

        // ---- pass B: rows row0+32..row0+63 ----
        compute_dispatch(range, xrB, ldsrow);
        lds_barrier();
        store_pass(out, row0 + 32, tid, lds);
        lds_barrier();
    }
}

extern "C" void kernel_launch(void* const* d_in, const int* in_sizes, int n_in,
                              void* d_out, int out_size, void* d_ws, size_t ws_size,
                              hipStream_t stream) {
    const float* x = (const float*)d_in[0];
    float* out = (float*)d_out;
    // 256 blocks (1 per CU, LDS-capped), 8 waves each, 4 tiles of 64 rows.
    poly_rows<<<256, NTHREADS, 0, stream>>>(x, out);
}

// Round 15
// 51.514 us; speedup vs baseline: 1.0920x; 1.0920x over previous
//
#include <hip/hip_runtime.h>
#include <stdint.h>

#define NFEAT 16
#define NCOLS 969            // 1 bias + 16 deg1 + 136 deg2 + 816 deg3
#define NROWS 65536
#define PROWS 16             // rows per pass (double-buffered)
#define NPASS 16             // 256 rows per block / 16
#define NTHREADS 512
#define NPASS_F4 (PROWS * NCOLS / 4)   // 3876 float4 groups per pass

typedef float floatx4 __attribute__((ext_vector_type(4)));

// ---------------------------------------------------------------------------
// Static compute of cols [CB, CE) of one row into packed LDS row (stride 969).
// All 969 columns emitted in sklearn/jax reference order (verified absmax 0.0
// R1/R3-R14); out-of-range emits are compile-time dead. Scalar ds_write_b32:
// 16 rows x stride 969 (%32 = 9, coprime) -> all 16 lanes of a group hit
// distinct banks: conflict-free.
// ---------------------------------------------------------------------------
template<int CB, int CE>
__device__ __forceinline__ void compute_range(const float* xr, float* ldsrow) {
    int col = 0;
#define EMIT(P) do { if (col >= CB && col < CE) ldsrow[col] = (P); ++col; } while (0)
    EMIT(1.0f);                                   // bias
    #pragma unroll
    for (int i = 0; i < NFEAT; ++i) EMIT(xr[i]);  // degree 1
    #pragma unroll
    for (int i = 0; i < NFEAT; ++i)               // degree 2
        #pragma unroll
        for (int j = i; j < NFEAT; ++j) EMIT(xr[i] * xr[j]);
    #pragma unroll
    for (int i = 0; i < NFEAT; ++i)               // degree 3
        #pragma unroll
        for (int j = i; j < NFEAT; ++j)
            #pragma unroll
            for (int k = j; k < NFEAT; ++k) EMIT((xr[i] * xr[j]) * xr[k]);
#undef EMIT
}

// 32 column ranges: r*30 .. (r+1)*30 (last: 930..969). Uniform per 16-lane group.
#define RANGE_B(R) ((R) * 30)
#define RANGE_E(R) ((R) == 31 ? 969 : ((R) + 1) * 30)

// ---------------------------------------------------------------------------
// Interleaved pass: 8 steps of { store one f4 group of src buf -> out,
// compute one ~4-col sub-slice of the NEXT pass into the other buf }.
// Store instructions are spread through the compute so the VMEM queue is
// refilled the moment drain frees a slot -> HBM never idles.
// ---------------------------------------------------------------------------
template<int CB, int CE>
__device__ __forceinline__ void islice_pass(const float* xr, float* ldsrow_next,
                                            const floatx4* src4, floatx4* dst4,
                                            int tid) {
    constexpr int W = (CE - CB + 7) / 8;
#define STEP(S) do { \
        int g4 = tid + (S) * NTHREADS; \
        if (g4 < NPASS_F4) dst4[g4] = src4[g4]; \
        constexpr int b_ = CB + (S) * W; \
        constexpr int e_ = (b_ + W < CE) ? (b_ + W) : CE; \
        if constexpr (b_ < CE) compute_range<b_, e_>(xr, ldsrow_next); \
    } while (0)
    STEP(0); STEP(1); STEP(2); STEP(3); STEP(4); STEP(5); STEP(6); STEP(7);
#undef STEP
}

// Raw barrier WITHOUT vmcnt drain: LDS visibility needs only lgkmcnt(0);
// in-flight global stores keep draining across it.
__device__ __forceinline__ void lds_barrier() {
    asm volatile("s_waitcnt lgkmcnt(0)" ::: "memory");
    __builtin_amdgcn_s_barrier();
}

__global__ void __launch_bounds__(NTHREADS, 1)
poly_il(const float* __restrict__ x, float* __restrict__ out) {
    __shared__ __align__(16) float buf[2][PROWS * NCOLS];   // 2 x 62,016 B

    const int tid   = threadIdx.x;
    const int xrow  = tid & 15;                  // row within pass
    const int range = tid >> 4;                  // 0..31, uniform per 16-lane group
    const int base  = blockIdx.x * (NPASS * PROWS);   // 256 rows per block

    // ---- prologue: load x(pass 0), compute pass 0 into buf[0] ----
    const floatx4* xp = (const floatx4*)(x + (size_t)(base + xrow) * NFEAT);
    floatx4 c0 = xp[0], c1 = xp[1], c2 = xp[2], c3 = xp[3];
    float xr[NFEAT] = {c0[0],c0[1],c0[2],c0[3], c1[0],c1[1],c1[2],c1[3],
                       c2[0],c2[1],c2[2],c2[3], c3[0],c3[1],c3[2],c3[3]};
    // issue prefetch of x(pass 1) before computing
    const floatx4* xq = (const floatx4*)(x + (size_t)(base + PROWS + xrow) * NFEAT);
    floatx4 n0 = xq[0], n1 = xq[1], n2 = xq[2], n3 = xq[3];

    float* ldsrow0 = &buf[0][xrow * NCOLS];
    switch (range) {
#define CCASE(R) case R: compute_range<RANGE_B(R), RANGE_E(R)>(xr, ldsrow0); break;
        CCASE(0)  CCASE(1)  CCASE(2)  CCASE(3)  CCASE(4)  CCASE(5)  CCASE(6)  CCASE(7)
        CCASE(8)  CCASE(9)  CCASE(10) CCASE(11) CCASE(12) CCASE(13) CCASE(14) CCASE(15)
        CCASE(16) CCASE(17) CCASE(18) CCASE(19) CCASE(20) CCASE(21) CCASE(22) CCASE(23)
        CCASE(24) CCASE(25) CCASE(26) CCASE(27) CCASE(28) CCASE(29) CCASE(30) CCASE(31)
#undef CCASE
    }
    lds_barrier();

    // ---- main loop: store pass p (interleaved) + compute pass p+1 ----
    for (int p = 0; p < NPASS - 1; ++p) {
        // extract x(pass p+1) (compiler inserts the vmcnt wait here)
        float xr2[NFEAT] = {n0[0],n0[1],n0[2],n0[3], n1[0],n1[1],n1[2],n1[3],
                            n2[0],n2[1],n2[2],n2[3], n3[0],n3[1],n3[2],n3[3]};
        // issue prefetch of x(pass p+2); has a whole pass (~5.4k cyc) to land
        if (p + 2 < NPASS) {
            const floatx4* xn = (const floatx4*)
                (x + (size_t)(base + (p + 2) * PROWS + xrow) * NFEAT);
            n0 = xn[0]; n1 = xn[1]; n2 = xn[2]; n3 = xn[3];
        }

        const floatx4* src4 = (const floatx4*)buf[p & 1];
        float* ldsrow_next  = &buf[(p + 1) & 1][xrow * NCOLS];
        floatx4* dst4 = (floatx4*)(out + (size_t)(base + p * PROWS) * NCOLS);

        switch (range) {
#define ICASE(R) case R: islice_pass<RANGE_B(R), RANGE_E(R)>(xr2, ldsrow_next, src4, dst4, tid); break;
            ICASE(0)  ICASE(1)  ICASE(2)  ICASE(3)  ICASE(4)  ICASE(5)  ICASE(6)  ICASE(7)
            ICASE(8)  ICASE(9)  ICASE(10) ICASE(11) ICASE(12) ICASE(13) ICASE(14) ICASE(15)
            ICASE(16) ICASE(17) ICASE(18) ICASE(19) ICASE(20) ICASE(21) ICASE(22) ICASE(23)
            ICASE(24) ICASE(25) ICASE(26) ICASE(27) ICASE(28) ICASE(29) ICASE(30) ICASE(31)
#undef ICASE
        }
        lds_barrier();
    }

    // ---- epilogue: store pass 15 (no compute) ----
    {
        const floatx4* src4 = (const floatx4*)buf[(NPASS - 1) & 1];
        floatx4* dst4 = (floatx4*)(out + (size_t)(base + (NPASS - 1) * PROWS) * NCOLS);
        #pragma unroll
        for (int s = 0; s < 8; ++s) {
            int g4 = tid + s * NTHREADS;
            if (g4 < NPASS_F4) dst4[g4] = src4[g4];
        }
    }
}

extern "C" void kernel_launch(void* const* d_in, const int* in_sizes, int n_in,
                              void* d_out, int out_size, void* d_ws, size_t ws_size,
                              hipStream_t stream) {
    const float* x = (const float*)d_in[0];
    float* out = (float*)d_out;
    // 256 persistent blocks (1 per CU), 16 double-buffered 16-row passes.
    poly_il<<<256, NTHREADS, 0, stream>>>(x, out);
}

// Round 16
// 44.231 us; speedup vs baseline: 1.2718x; 1.1646x over previous
//
#include <hip/hip_runtime.h>
#include <stdint.h>

#define NFEAT 16
#define NCOLS 969            // 1 bias + 16 deg1 + 136 deg2 + 816 deg3
#define NROWS 65536
#define PROWS 16             // rows per pass (double-buffered)
#define NPASS 16             // 256 rows per block / 16
#define NTHREADS 512
#define PASS_F4 (PROWS * NCOLS / 4)   // 3876 float4 groups per pass

typedef float floatx4 __attribute__((ext_vector_type(4)));

// ---------------------------------------------------------------------------
// Static compute of cols [CB, CE) of one row into packed LDS row (stride 969).
// All 969 columns emitted in sklearn/jax reference order (verified absmax 0.0
// R1/R3-R15); out-of-range emits are compile-time dead. Scalar ds_write_b32:
// 16 rows x stride 969 (969%32=9, gcd(9,32)=1) -> 16 lanes hit 16 distinct
// banks: conflict-free.
// ---------------------------------------------------------------------------
template<int CB, int CE>
__device__ __forceinline__ void compute_range(const float* xr, float* ldsrow) {
    int col = 0;
#define EMIT(P) do { if (col >= CB && col < CE) ldsrow[col] = (P); ++col; } while (0)
    EMIT(1.0f);                                   // bias
    #pragma unroll
    for (int i = 0; i < NFEAT; ++i) EMIT(xr[i]);  // degree 1
    #pragma unroll
    for (int i = 0; i < NFEAT; ++i)               // degree 2
        #pragma unroll
        for (int j = i; j < NFEAT; ++j) EMIT(xr[i] * xr[j]);
    #pragma unroll
    for (int i = 0; i < NFEAT; ++i)               // degree 3 (x_i*x_j via CSE)
        #pragma unroll
        for (int j = i; j < NFEAT; ++j)
            #pragma unroll
            for (int k = j; k < NFEAT; ++k) EMIT((xr[i] * xr[j]) * xr[k]);
#undef EMIT
}

__device__ __forceinline__ void compute_dispatch(int range, const float* xr, float* ldsrow) {
    switch (range) {   // uniform per 16-lane group; 4 serial bodies per wave
        case  0: compute_range<  0,  60>(xr, ldsrow); break;
        case  1: compute_range< 60, 120>(xr, ldsrow); break;
        case  2: compute_range<120, 180>(xr, ldsrow); break;
        case  3: compute_range<180, 240>(xr, ldsrow); break;
        case  4: compute_range<240, 300>(xr, ldsrow); break;
        case  5: compute_range<300, 360>(xr, ldsrow); break;
        case  6: compute_range<360, 420>(xr, ldsrow); break;
        case  7: compute_range<420, 480>(xr, ldsrow); break;
        case  8: compute_range<480, 540>(xr, ldsrow); break;
        case  9: compute_range<540, 600>(xr, ldsrow); break;
        case 10: compute_range<600, 660>(xr, ldsrow); break;
        case 11: compute_range<660, 720>(xr, ldsrow); break;
        case 12: compute_range<720, 780>(xr, ldsrow); break;
        case 13: compute_range<780, 840>(xr, ldsrow); break;
        case 14: compute_range<840, 900>(xr, ldsrow); break;
        case 15: compute_range<900, 969>(xr, ldsrow); break;
    }
}

// Raw barrier WITHOUT vmcnt drain: LDS visibility needs only lgkmcnt(0);
// in-flight global stores keep draining across it.
__device__ __forceinline__ void lds_barrier() {
    asm volatile("s_waitcnt lgkmcnt(0)" ::: "memory");
    __builtin_amdgcn_s_barrier();
}

// ---------------------------------------------------------------------------
// Producer/consumer, 4+4 waves (R12 retry with the capacity fix):
//   waves 0-3 (tid 0..255):   compute 16-row passes into buf[p&1]
//   waves 4-7 (tid 256..511): batched flat copy buf[p&1] -> out
// Consumer batches 8 ds_read_b128 then 8 global_store_dwordx4 back-to-back:
// ~8-15 KB in flight per wave, 4 waves -> 32-60 KB/CU (R12's 2-wave/8KB
// starved HBM at 6.2 B/cyc; 11.4 needed). Store waves stall on vmcnt
// register-reuse harmlessly; producers never wait on vmem.
// Barrier pairing (16 each side, proven race-free in R12):
//   producer: [compute p; lgkm; bar] x16   consumer: [bar; copy p] x16
// Producer writes buf[(p+1)&1] while consumer reads buf[p&1] -> disjoint.
// NOTE: no VGPR cap -- __launch_bounds__(512,1) (R7/R8/R9 spill lesson).
// ---------------------------------------------------------------------------
__global__ void __launch_bounds__(NTHREADS, 1)
poly_pc(const float* __restrict__ x, float* __restrict__ out) {
    __shared__ __align__(16) float buf[2][PROWS * NCOLS];   // 2 x 62,016 B

    const int tid  = threadIdx.x;
    const int base = blockIdx.x * (NPASS * PROWS);          // 256 rows per block

    if (tid < 256) {
        // ---------------- producers (waves 0-3) ----------------
        const int prow  = tid & 15;          // row within pass
        const int range = tid >> 4;          // 0..15
        const floatx4* xv = (const floatx4*)(x + (size_t)(base + prow) * NFEAT);
        floatx4 c0 = xv[0], c1 = xv[1], c2 = xv[2], c3 = xv[3];

        for (int p = 0; p < NPASS; ++p) {
            float xr[NFEAT] = {c0[0],c0[1],c0[2],c0[3], c1[0],c1[1],c1[2],c1[3],
                               c2[0],c2[1],c2[2],c2[3], c3[0],c3[1],c3[2],c3[3]};
            // prefetch next pass's x-row; has a full pass (~5.4k cyc) to land
            if (p + 1 < NPASS) {
                const floatx4* nv = (const floatx4*)
                    (x + (size_t)(base + (p + 1) * PROWS + prow) * NFEAT);
                c0 = nv[0]; c1 = nv[1]; c2 = nv[2]; c3 = nv[3];
            }
            compute_dispatch(range, xr, &buf[p & 1][prow * NCOLS]);
            lds_barrier();                                   // barrier p
        }
    } else {
        // ---------------- consumers (waves 4-7) ----------------
        const int ctid = tid - 256;          // 0..255
        for (int p = 0; p < NPASS; ++p) {
            lds_barrier();                                   // barrier p
            const floatx4* src4 = (const floatx4*)buf[p & 1];
            floatx4* dst4 = (floatx4*)(out + (size_t)(base + p * PROWS) * NCOLS);

            // batch 1: groups ctid + {0..7}*256  (all < 3876)
            floatx4 r[8];
            #pragma unroll
            for (int s = 0; s < 8; ++s) r[s] = src4[ctid + s * 256];
            #pragma unroll
            for (int s = 0; s < 8; ++s) dst4[ctid + s * 256] = r[s];

            // batch 2: groups ctid + {8..14}*256 (max 3839 < 3876) + tail s=15
            floatx4 q[7];
            #pragma unroll
            for (int s = 0; s < 7; ++s) q[s] = src4[ctid + (s + 8) * 256];
            floatx4 t;
            if (ctid < PASS_F4 - 3840) t = src4[ctid + 3840];   // 36 lanes
            #pragma unroll
            for (int s = 0; s < 7; ++s) dst4[ctid + (s + 8) * 256] = q[s];
            if (ctid < PASS_F4 - 3840) dst4[ctid + 3840] = t;
        }
    }
}

extern "C" void kernel_launch(void* const* d_in, const int* in_sizes, int n_in,
                              void* d_out, int out_size, void* d_ws, size_t ws_size,
                              hipStream_t stream) {
    const float* x = (const float*)d_in[0];
    float* out = (float*)d_out;
    // 256 persistent blocks (1 per CU), 16 double-buffered 16-row passes,
    // 4 producer + 4 consumer waves.
    poly_pc<<<256, NTHREADS, 0, stream>>>(x, out);
}